// Round 2
// baseline (502.904 us; speedup 1.0000x reference)
//
#include <hip/hip_runtime.h>

#define B_ 64
#define N_ 2048
#define D_ 256
#define H_ 8
#define LARGE_ 1e9f
#define EPS_ 1e-10f

typedef __attribute__((ext_vector_type(4))) float f32x4;
typedef __attribute__((ext_vector_type(8))) short s16x8;

// workspace layout (bytes) — total 9,766,912
#define WS_QKBF 0          // qk A-frag bf16: 64 b * 8 kblk * 64 lane * 8 = 524288
#define WS_WGP  524288     // gating_w pack bf16 = 131072
#define WS_QPART 655360    // q partial sums [512][256] f32 = 524288
#define WS_MPART 1179648   // mask partial sums [512] f32 = 2048
#define WS_MX   1181696    // chunk max [64][32][8] f32 = 65536
#define WS_SM   1247232    // chunk expsum [64][32][8] f32 = 65536
#define WS_WA   1312768    // combined weighted_avg [64][256] f32 = 65536
#define WS_WMP  1378304    // wm partials bf16 [64*32][256][8] = 8388608 (ends 9766912)
#define WS_WPP  1378304    // per-batch output pack bf16 = 8388608 — overlays WS_WMP
                           // (wm_part dead after kF1; kF2 writes wpp after kF1 completes)

__device__ __forceinline__ unsigned short f2bf(float f) {
  union { float f; unsigned u; } v; v.f = f;
  unsigned r = v.u + 0x7fffu + ((v.u >> 16) & 1u);
  return (unsigned short)(r >> 16);
}
__device__ __forceinline__ float bf2f(unsigned short s) {
  union { unsigned u; float f; } v; v.u = ((unsigned)s) << 16;
  return v.f;
}

// ---------------- kA: masked q-sum partials (NO global atomics) + Wg pack (UNCHANGED)
__global__ void kA(const float* __restrict__ q_data, const float* __restrict__ q_mask,
                   const float* __restrict__ gating_w, float* __restrict__ qpart,
                   float* __restrict__ mpart, unsigned short* __restrict__ wgp) {
  int blk = blockIdx.x, t = threadIdx.x;
  if (blk < 512) {
    int b = blk >> 3, n0 = (blk & 7) * 256;
    __shared__ float msk[256];
    __shared__ float qred[4][256];
    __shared__ float mred[4];
    msk[t] = q_mask[b * N_ + n0 + t];
    __syncthreads();
    int w = t >> 6, d4 = t & 63;
    const float* qbase = q_data + ((size_t)(b * N_ + n0)) * D_;
    f32x4 acc = {0.f, 0.f, 0.f, 0.f};
    #pragma unroll 4
    for (int i = 0; i < 64; ++i) {
      int r = i * 4 + w;
      f32x4 v = *(const f32x4*)(qbase + (size_t)r * D_ + d4 * 4);
      float mk = msk[r];
      acc += v * mk;
    }
    *(f32x4*)(&qred[w][d4 * 4]) = acc;
    float mv = msk[t];
    for (int off = 32; off; off >>= 1) mv += __shfl_xor(mv, off);
    if ((t & 63) == 0) mred[t >> 6] = mv;
    __syncthreads();
    qpart[((size_t)blk) * 256 + t] = qred[0][t] + qred[1][t] + qred[2][t] + qred[3][t];
    if (t == 0) mpart[blk] = mred[0] + mred[1] + mred[2] + mred[3];
  } else {
    int base = (blk - 512) * 1024;
    for (int i = 0; i < 4; ++i) {
      int a = base + i * 256 + t;
      int sc = a >> 9, l = (a >> 3) & 63, j = a & 7;
      int s = sc >> 4, c = sc & 15, lh = l >> 4, ll = l & 15;
      int k = s * 32 + lh * 8 + j, n = c * 16 + ll;
      wgp[a] = f2bf(gating_w[k * 256 + n]);
    }
  }
}

// ---------------- kB: reduce partials -> q_avg -> q -> qk bf16 A-frag (UNCHANGED)
__global__ void kB(const float* __restrict__ qpart, const float* __restrict__ mpart,
                   const float* __restrict__ query_w, const float* __restrict__ key_w,
                   unsigned short* __restrict__ qkbf) {
  int b = blockIdx.x, t = threadIdx.x;
  __shared__ float qa[256];
  __shared__ float ql[256];
  float s = 0.f;
  #pragma unroll
  for (int p = 0; p < 8; ++p) s += qpart[((size_t)(b * 8 + p)) * 256 + t];
  float ms = 0.f;
  #pragma unroll
  for (int p = 0; p < 8; ++p) ms += mpart[b * 8 + p];
  qa[t] = s / (ms + EPS_);
  __syncthreads();
  float acc = 0.f;
  #pragma unroll 4
  for (int a = 0; a < 256; ++a) acc += qa[a] * query_w[a * 256 + t];
  ql[t] = acc * 0.17677669529663687f;  // * KD^-0.5
  __syncthreads();
  float v8[8];
  #pragma unroll
  for (int h = 0; h < 8; ++h) {
    float v = 0.f;
    #pragma unroll
    for (int c = 0; c < 32; ++c) v += key_w[t * 32 + c] * ql[h * 32 + c];
    v8[h] = v;
  }
  int si = t >> 5, lh = (t >> 3) & 3, j = t & 7;
  unsigned short* base = qkbf + ((size_t)(b * 8 + si) * 64) * 8;
  #pragma unroll
  for (int h = 0; h < 8; ++h) {
    base[(lh * 16 + h) * 8 + j] = f2bf(v8[h]);
    base[(lh * 16 + 8 + h) * 8 + j] = 0;
  }
}

// ---------------- kM: FUSED logits(MFMA) + online softmax + weighted partial sum (UNCHANGED)
__global__ void kM(const float* __restrict__ m_data, const float* __restrict__ q_mask,
                   const unsigned short* __restrict__ qkbf, unsigned short* __restrict__ wm_part,
                   float* __restrict__ mx_part, float* __restrict__ sm_part) {
  int b = blockIdx.y, ch = blockIdx.x, n0 = ch * 64, t = threadIdx.x;
  __shared__ __align__(16) unsigned char sM[64 * 528];
  __shared__ f32x4 pW[64][2];   // exp weights per row: [0]=h0..3, [1]=h4..7
  __shared__ float red[4][8];
  __shared__ float hval[8];
  {
    int w = t >> 6, d4 = t & 63;
    #pragma unroll
    for (int i = 0; i < 16; ++i) {
      int r = i * 4 + w;
      f32x4 v = *(const f32x4*)(m_data + ((size_t)(b * N_ + n0 + r)) * D_ + d4 * 4);
      uint2 pp;
      pp.x = f2bf(v[0]) | ((unsigned)f2bf(v[1]) << 16);
      pp.y = f2bf(v[2]) | ((unsigned)f2bf(v[3]) << 16);
      *(uint2*)(sM + r * 528 + d4 * 8) = pp;
    }
  }
  __syncthreads();
  int lane = t & 63, w = t >> 6;
  int l15 = lane & 15, lhi = lane >> 4;
  const s16x8* A = (const s16x8*)qkbf + (size_t)b * 512;
  s16x8 areg[8];
  #pragma unroll
  for (int s = 0; s < 8; ++s) areg[s] = A[s * 64 + lane];
  f32x4 acc = {0.f, 0.f, 0.f, 0.f};
  int nrow = w * 16 + l15;
  #pragma unroll
  for (int s = 0; s < 8; ++s) {
    s16x8 bfr = *(const s16x8*)(sM + nrow * 528 + s * 64 + lhi * 16);
    acc = __builtin_amdgcn_mfma_f32_16x16x32_bf16(areg[s], bfr, acc, 0, 0, 0);
  }
  float bias = LARGE_ * (q_mask[b * N_ + n0 + nrow] - 1.f);
  float lg[4];
  #pragma unroll
  for (int r = 0; r < 4; ++r) lg[r] = (lhi < 2) ? (acc[r] + bias) : -3.4e38f;
  #pragma unroll
  for (int off = 8; off; off >>= 1)
    #pragma unroll
    for (int r = 0; r < 4; ++r) lg[r] = fmaxf(lg[r], __shfl_xor(lg[r], off));
  if (l15 == 0 && lhi < 2)
    #pragma unroll
    for (int r = 0; r < 4; ++r) red[w][lhi * 4 + r] = lg[r];
  __syncthreads();
  if (t < 8) {
    float m = fmaxf(fmaxf(red[0][t], red[1][t]), fmaxf(red[2][t], red[3][t]));
    hval[t] = m;
    mx_part[((size_t)(b * 32 + ch)) * 8 + t] = m;
  }
  __syncthreads();
  float pv[4], ps[4];
  #pragma unroll
  for (int r = 0; r < 4; ++r) {
    float M = hval[(lhi & 1) * 4 + r];
    float e = __expf(acc[r] + bias - M);
    pv[r] = e;
    ps[r] = (lhi < 2) ? e : 0.f;
  }
  if (lhi < 2) {
    f32x4 pq = {pv[0], pv[1], pv[2], pv[3]};
    pW[nrow][lhi] = pq;
  }
  #pragma unroll
  for (int off = 8; off; off >>= 1)
    #pragma unroll
    for (int r = 0; r < 4; ++r) ps[r] += __shfl_xor(ps[r], off);
  if (l15 == 0 && lhi < 2)
    #pragma unroll
    for (int r = 0; r < 4; ++r) red[w][lhi * 4 + r] = ps[r];
  __syncthreads();
  if (t < 8)
    sm_part[((size_t)(b * 32 + ch)) * 8 + t] = red[0][t] + red[1][t] + red[2][t] + red[3][t];
  f32x4 vacc[8];
  #pragma unroll
  for (int h = 0; h < 8; ++h) vacc[h] = (f32x4){0.f, 0.f, 0.f, 0.f};
  #pragma unroll 4
  for (int i = 0; i < 16; ++i) {
    int r = w * 16 + i;
    uint2 pp = *(const uint2*)(sM + r * 528 + lane * 8);
    f32x4 mv;
    mv[0] = bf2f(pp.x & 0xffff); mv[1] = bf2f(pp.x >> 16);
    mv[2] = bf2f(pp.y & 0xffff); mv[3] = bf2f(pp.y >> 16);
    f32x4 w0 = pW[r][0], w1 = pW[r][1];
    vacc[0] += mv * w0[0]; vacc[1] += mv * w0[1]; vacc[2] += mv * w0[2]; vacc[3] += mv * w0[3];
    vacc[4] += mv * w1[0]; vacc[5] += mv * w1[1]; vacc[6] += mv * w1[2]; vacc[7] += mv * w1[3];
  }
  __syncthreads();
  float* red2 = (float*)sM;
  #pragma unroll
  for (int h = 0; h < 8; ++h) *(f32x4*)(&red2[(w * 8 + h) * 256 + lane * 4]) = vacc[h];
  __syncthreads();
  float s8[8];
  #pragma unroll
  for (int h = 0; h < 8; ++h)
    s8[h] = red2[h * 256 + t] + red2[(8 + h) * 256 + t] + red2[(16 + h) * 256 + t] +
            red2[(24 + h) * 256 + t];
  uint4 u;
  u.x = f2bf(s8[0]) | ((unsigned)f2bf(s8[1]) << 16);
  u.y = f2bf(s8[2]) | ((unsigned)f2bf(s8[3]) << 16);
  u.z = f2bf(s8[4]) | ((unsigned)f2bf(s8[5]) << 16);
  u.w = f2bf(s8[6]) | ((unsigned)f2bf(s8[7]) << 16);
  *(uint4*)(wm_part + ((size_t)((b * 32 + ch) * 256 + t)) * 8) = u;
}

// ---------------- kF1: combine chunk partials with max-rescale -> wa (UNCHANGED)
__global__ void kF1(const unsigned short* __restrict__ wm_part, const float* __restrict__ mx_part,
                    const float* __restrict__ sm_part, const float* __restrict__ value_w,
                    float* __restrict__ wa_g) {
  int b = blockIdx.x, t = threadIdx.x;
  __shared__ float s_mx[256], s_sm[256], scl[256];
  __shared__ float gmx[8], gden[8];
  __shared__ float wml[8][256];
  s_mx[t] = mx_part[(size_t)b * 256 + t];
  s_sm[t] = sm_part[(size_t)b * 256 + t];
  __syncthreads();
  if (t < 8) {
    float m = -3.4e38f;
    for (int c = 0; c < 32; ++c) m = fmaxf(m, s_mx[c * 8 + t]);
    gmx[t] = m;
  }
  __syncthreads();
  scl[t] = __expf(s_mx[t] - gmx[t & 7]);
  __syncthreads();
  if (t < 8) {
    float d = 0.f;
    for (int c = 0; c < 32; ++c) d += s_sm[c * 8 + t] * scl[c * 8 + t];
    gden[t] = d;
  }
  float acc[8] = {0.f, 0.f, 0.f, 0.f, 0.f, 0.f, 0.f, 0.f};
  for (int c = 0; c < 32; ++c) {
    uint4 u = *(const uint4*)(wm_part + ((size_t)((b * 32 + c) * 256 + t)) * 8);
    const float* sc = &scl[c * 8];
    acc[0] += bf2f(u.x & 0xffff) * sc[0]; acc[1] += bf2f(u.x >> 16) * sc[1];
    acc[2] += bf2f(u.y & 0xffff) * sc[2]; acc[3] += bf2f(u.y >> 16) * sc[3];
    acc[4] += bf2f(u.z & 0xffff) * sc[4]; acc[5] += bf2f(u.z >> 16) * sc[5];
    acc[6] += bf2f(u.w & 0xffff) * sc[6]; acc[7] += bf2f(u.w >> 16) * sc[7];
  }
  #pragma unroll
  for (int h = 0; h < 8; ++h) wml[h][t] = acc[h];
  __syncthreads();
  int h = t >> 5, v = t & 31;
  float s = 0.f;
  #pragma unroll 4
  for (int d = 0; d < 256; ++d) s += wml[h][d] * value_w[d * 32 + v];
  wa_g[b * 256 + t] = s / gden[h];
}

// ---------------- kF2: pack W'[b] = diag(wa)*output_w — NOW with coalesced LDS staging
// (old version gathered output_w 4B-per-lane across 64 lines per wave-load; now we stage
//  32 rows of output_w coalesced into padded LDS per half and gather from LDS instead)
__global__ void kF2(const float* __restrict__ wa_g, const float* __restrict__ output_w,
                    unsigned short* __restrict__ wpp) {
  int blk = blockIdx.x, t = threadIdx.x;
  int b = blk >> 2, quad = blk & 3;
  __shared__ float sOW[32 * 260];  // stride 260 f32: 16B-aligned rows, conflict-free gather
  __shared__ float wa[256];
  wa[t] = wa_g[b * 256 + t];
  unsigned short* wp = wpp + (size_t)b * 65536;
  for (int half = 0; half < 2; ++half) {
    int srow = quad * 64 + half * 32;  // = s*32 for s = 2*quad + half
    __syncthreads();                    // protects sOW reuse; covers wa on first pass
    const f32x4* src = (const f32x4*)(output_w + srow * 256);
    #pragma unroll
    for (int i = 0; i < 8; ++i) {
      int idx4 = i * 256 + t;           // 2048 x f32x4 = 32 rows * 256 f32
      f32x4 v = src[idx4];
      int rr = idx4 >> 6, c4 = idx4 & 63;
      *(f32x4*)(&sOW[rr * 260 + c4 * 4]) = v;
    }
    __syncthreads();
    int abase = quad * 16384 + half * 8192;
    for (int it = 0; it < 32; ++it) {
      int a = abase + it * 256 + t;
      int sc = a >> 9, l = (a >> 3) & 63, j = a & 7;
      int c = sc & 15, lh = l >> 4, ll = l & 15;
      int hvl = lh * 8 + j, o = c * 16 + ll;  // hvl = hv - srow, verified: s = 2q+half here
      wp[a] = f2bf(wa[srow + hvl] * sOW[hvl * 260 + o]);
    }
  }
}

// ---------------- kG: 32-row tiles for occupancy (LDS 33.8K -> 16.9K, acc 16 -> 8)
__global__ void __launch_bounds__(256, 6) kG(
    const float* __restrict__ q_data, const float* __restrict__ gating_b,
    const float* __restrict__ output_b, const unsigned short* __restrict__ wgp,
    const unsigned short* __restrict__ wpp, float* __restrict__ out) {
  int b = blockIdx.y, row0 = blockIdx.x * 32, t = threadIdx.x;
  __shared__ __align__(16) unsigned char sG[32 * 528];
  {
    int w = t >> 6, d4 = t & 63;
    #pragma unroll
    for (int i = 0; i < 8; ++i) {
      int r = i * 4 + w;
      f32x4 v = *(const f32x4*)(q_data + ((size_t)(b * N_ + row0 + r)) * D_ + d4 * 4);
      uint2 pp;
      pp.x = f2bf(v[0]) | ((unsigned)f2bf(v[1]) << 16);
      pp.y = f2bf(v[2]) | ((unsigned)f2bf(v[3]) << 16);
      *(uint2*)(sG + r * 528 + d4 * 8) = pp;
    }
  }
  __syncthreads();
  int lane = t & 63, cg = t >> 6;
  int l15 = lane & 15, lhi = lane >> 4;
  const f32x4 z = {0.f, 0.f, 0.f, 0.f};
  f32x4 acc[8];
  #pragma unroll
  for (int f = 0; f < 8; ++f) acc[f] = z;
  const s16x8* Bg = (const s16x8*)wgp;
  #pragma unroll
  for (int s = 0; s < 8; ++s) {
    s16x8 af[2], bfr[4];
    #pragma unroll
    for (int rt = 0; rt < 2; ++rt)
      af[rt] = *(const s16x8*)(sG + (rt * 16 + l15) * 528 + s * 64 + lhi * 16);
    #pragma unroll
    for (int ct = 0; ct < 4; ++ct) bfr[ct] = Bg[(s * 16 + cg * 4 + ct) * 64 + lane];
    #pragma unroll
    for (int rt = 0; rt < 2; ++rt)
      #pragma unroll
      for (int ct = 0; ct < 4; ++ct)
        acc[rt * 4 + ct] =
            __builtin_amdgcn_mfma_f32_16x16x32_bf16(af[rt], bfr[ct], acc[rt * 4 + ct], 0, 0, 0);
  }
  __syncthreads();
  {
    float gb[4];
    #pragma unroll
    for (int ct = 0; ct < 4; ++ct) gb[ct] = gating_b[cg * 64 + ct * 16 + l15];
    #pragma unroll
    for (int rt = 0; rt < 2; ++rt)
      #pragma unroll
      for (int ct = 0; ct < 4; ++ct) {
        int col = cg * 64 + ct * 16 + l15;
        #pragma unroll
        for (int r = 0; r < 4; ++r) {
          float x = acc[rt * 4 + ct][r] + gb[ct];
          float g = 1.f / (1.f + __expf(-x));
          int row = rt * 16 + lhi * 4 + r;
          *(unsigned short*)(sG + row * 528 + col * 2) = f2bf(g);
        }
      }
  }
  __syncthreads();
  #pragma unroll
  for (int f = 0; f < 8; ++f) acc[f] = z;
  const s16x8* Bp = (const s16x8*)wpp + (size_t)b * 8192;
  #pragma unroll
  for (int s = 0; s < 8; ++s) {
    s16x8 af[2], bfr[4];
    #pragma unroll
    for (int rt = 0; rt < 2; ++rt)
      af[rt] = *(const s16x8*)(sG + (rt * 16 + l15) * 528 + s * 64 + lhi * 16);
    #pragma unroll
    for (int ct = 0; ct < 4; ++ct) bfr[ct] = Bp[(s * 16 + cg * 4 + ct) * 64 + lane];
    #pragma unroll
    for (int rt = 0; rt < 2; ++rt)
      #pragma unroll
      for (int ct = 0; ct < 4; ++ct)
        acc[rt * 4 + ct] =
            __builtin_amdgcn_mfma_f32_16x16x32_bf16(af[rt], bfr[ct], acc[rt * 4 + ct], 0, 0, 0);
  }
  __syncthreads();
  float* fOut = (float*)sG;  // 16 rows * 260 f32 = 16640 B <= 16896 B
  float ob[4];
  #pragma unroll
  for (int ct = 0; ct < 4; ++ct) ob[ct] = output_b[cg * 64 + ct * 16 + l15];
  #pragma unroll
  for (int p = 0; p < 2; ++p) {  // p = row-tile rt
    #pragma unroll
    for (int ct = 0; ct < 4; ++ct) {
      int col = cg * 64 + ct * 16 + l15;
      #pragma unroll
      for (int r = 0; r < 4; ++r)
        fOut[(lhi * 4 + r) * 260 + col] = acc[p * 4 + ct][r] + ob[ct];
    }
    __syncthreads();
    {
      int w = t >> 6, c4 = t & 63;
      #pragma unroll
      for (int j = 0; j < 4; ++j) {
        int r16 = j * 4 + w;
        f32x4 v = *(const f32x4*)(fOut + r16 * 260 + c4 * 4);
        *(f32x4*)(out + ((size_t)(b * N_ + row0 + p * 16 + r16)) * D_ + c4 * 4) = v;
      }
    }
    __syncthreads();
  }
}

extern "C" void kernel_launch(void* const* d_in, const int* in_sizes, int n_in,
                              void* d_out, int out_size, void* d_ws, size_t ws_size,
                              hipStream_t stream) {
  const float* q_data   = (const float*)d_in[0];
  const float* m_data   = (const float*)d_in[1];
  const float* q_mask   = (const float*)d_in[2];
  const float* query_w  = (const float*)d_in[3];
  const float* key_w    = (const float*)d_in[4];
  const float* value_w  = (const float*)d_in[5];
  const float* gating_w = (const float*)d_in[6];
  const float* gating_b = (const float*)d_in[7];
  const float* output_w = (const float*)d_in[8];
  const float* output_b = (const float*)d_in[9];
  float* out = (float*)d_out;
  char* ws = (char*)d_ws;

  unsigned short* qkbf = (unsigned short*)(ws + WS_QKBF);
  unsigned short* wgp  = (unsigned short*)(ws + WS_WGP);
  float* qpart = (float*)(ws + WS_QPART);
  float* mpart = (float*)(ws + WS_MPART);
  float* mx    = (float*)(ws + WS_MX);
  float* sm    = (float*)(ws + WS_SM);
  float* wa    = (float*)(ws + WS_WA);
  unsigned short* wmp = (unsigned short*)(ws + WS_WMP);
  unsigned short* wpp = (unsigned short*)(ws + WS_WPP);

  kA<<<576, 256, 0, stream>>>(q_data, q_mask, gating_w, qpart, mpart, wgp);
  kB<<<64, 256, 0, stream>>>(qpart, mpart, query_w, key_w, qkbf);
  kM<<<dim3(32, 64), 256, 0, stream>>>(m_data, q_mask, qkbf, wmp, mx, sm);
  kF1<<<64, 256, 0, stream>>>(wmp, mx, sm, value_w, wa);
  kF2<<<256, 256, 0, stream>>>(wa, output_w, wpp);
  kG<<<dim3(64, 64), 256, 0, stream>>>(q_data, gating_b, output_b, wgp, wpp, out);
}

// Round 3
// 486.282 us; speedup vs baseline: 1.0342x; 1.0342x over previous
//
#include <hip/hip_runtime.h>

#define B_ 64
#define N_ 2048
#define D_ 256
#define H_ 8
#define LARGE_ 1e9f
#define EPS_ 1e-10f

typedef __attribute__((ext_vector_type(4))) float f32x4;
typedef __attribute__((ext_vector_type(8))) short s16x8;

// workspace layout (bytes) — total 9,766,912
#define WS_QKBF 0          // qk A-frag bf16: 64 b * 8 kblk * 64 lane * 8 = 524288
#define WS_WGP  524288     // gating_w pack bf16 = 131072
#define WS_QPART 655360    // q partial sums [512][256] f32 = 524288
#define WS_MPART 1179648   // mask partial sums [512] f32 = 2048
#define WS_MX   1181696    // chunk max [64][32][8] f32 = 65536
#define WS_SM   1247232    // chunk expsum [64][32][8] f32 = 65536
#define WS_WA   1312768    // (spare)
#define WS_WMP  1378304    // wm partials bf16 [64*32][256][8] = 8388608 (ends 9766912)
#define WS_WPP  1378304    // per-batch output pack bf16 = 8388608 — overlays WS_WMP
                           // (block b reads its wm_part slice fully before writing the
                           //  same region as wpp; separated by __syncthreads in kFX)

__device__ __forceinline__ unsigned short f2bf(float f) {
  union { float f; unsigned u; } v; v.f = f;
  unsigned r = v.u + 0x7fffu + ((v.u >> 16) & 1u);
  return (unsigned short)(r >> 16);
}
__device__ __forceinline__ float bf2f(unsigned short s) {
  union { unsigned u; float f; } v; v.u = ((unsigned)s) << 16;
  return v.f;
}

// ---------------- kA: masked q-sum partials (NO global atomics) + Wg pack (UNCHANGED)
__global__ void kA(const float* __restrict__ q_data, const float* __restrict__ q_mask,
                   const float* __restrict__ gating_w, float* __restrict__ qpart,
                   float* __restrict__ mpart, unsigned short* __restrict__ wgp) {
  int blk = blockIdx.x, t = threadIdx.x;
  if (blk < 512) {
    int b = blk >> 3, n0 = (blk & 7) * 256;
    __shared__ float msk[256];
    __shared__ float qred[4][256];
    __shared__ float mred[4];
    msk[t] = q_mask[b * N_ + n0 + t];
    __syncthreads();
    int w = t >> 6, d4 = t & 63;
    const float* qbase = q_data + ((size_t)(b * N_ + n0)) * D_;
    f32x4 acc = {0.f, 0.f, 0.f, 0.f};
    #pragma unroll 4
    for (int i = 0; i < 64; ++i) {
      int r = i * 4 + w;
      f32x4 v = *(const f32x4*)(qbase + (size_t)r * D_ + d4 * 4);
      float mk = msk[r];
      acc += v * mk;
    }
    *(f32x4*)(&qred[w][d4 * 4]) = acc;
    float mv = msk[t];
    for (int off = 32; off; off >>= 1) mv += __shfl_xor(mv, off);
    if ((t & 63) == 0) mred[t >> 6] = mv;
    __syncthreads();
    qpart[((size_t)blk) * 256 + t] = qred[0][t] + qred[1][t] + qred[2][t] + qred[3][t];
    if (t == 0) mpart[blk] = mred[0] + mred[1] + mred[2] + mred[3];
  } else {
    int base = (blk - 512) * 1024;
    for (int i = 0; i < 4; ++i) {
      int a = base + i * 256 + t;
      int sc = a >> 9, l = (a >> 3) & 63, j = a & 7;
      int s = sc >> 4, c = sc & 15, lh = l >> 4, ll = l & 15;
      int k = s * 32 + lh * 8 + j, n = c * 16 + ll;
      wgp[a] = f2bf(gating_w[k * 256 + n]);
    }
  }
}

// ---------------- kB: reduce partials -> q_avg -> q -> qk bf16 A-frag (UNCHANGED)
__global__ void kB(const float* __restrict__ qpart, const float* __restrict__ mpart,
                   const float* __restrict__ query_w, const float* __restrict__ key_w,
                   unsigned short* __restrict__ qkbf) {
  int b = blockIdx.x, t = threadIdx.x;
  __shared__ float qa[256];
  __shared__ float ql[256];
  float s = 0.f;
  #pragma unroll
  for (int p = 0; p < 8; ++p) s += qpart[((size_t)(b * 8 + p)) * 256 + t];
  float ms = 0.f;
  #pragma unroll
  for (int p = 0; p < 8; ++p) ms += mpart[b * 8 + p];
  qa[t] = s / (ms + EPS_);
  __syncthreads();
  float acc = 0.f;
  #pragma unroll 4
  for (int a = 0; a < 256; ++a) acc += qa[a] * query_w[a * 256 + t];
  ql[t] = acc * 0.17677669529663687f;  // * KD^-0.5
  __syncthreads();
  float v8[8];
  #pragma unroll
  for (int h = 0; h < 8; ++h) {
    float v = 0.f;
    #pragma unroll
    for (int c = 0; c < 32; ++c) v += key_w[t * 32 + c] * ql[h * 32 + c];
    v8[h] = v;
  }
  int si = t >> 5, lh = (t >> 3) & 3, j = t & 7;
  unsigned short* base = qkbf + ((size_t)(b * 8 + si) * 64) * 8;
  #pragma unroll
  for (int h = 0; h < 8; ++h) {
    base[(lh * 16 + h) * 8 + j] = f2bf(v8[h]);
    base[(lh * 16 + 8 + h) * 8 + j] = 0;
  }
}

// ---------------- kM: FUSED logits(MFMA) + online softmax + weighted partial sum (UNCHANGED)
__global__ void kM(const float* __restrict__ m_data, const float* __restrict__ q_mask,
                   const unsigned short* __restrict__ qkbf, unsigned short* __restrict__ wm_part,
                   float* __restrict__ mx_part, float* __restrict__ sm_part) {
  int b = blockIdx.y, ch = blockIdx.x, n0 = ch * 64, t = threadIdx.x;
  __shared__ __align__(16) unsigned char sM[64 * 528];
  __shared__ f32x4 pW[64][2];   // exp weights per row: [0]=h0..3, [1]=h4..7
  __shared__ float red[4][8];
  __shared__ float hval[8];
  {
    int w = t >> 6, d4 = t & 63;
    #pragma unroll
    for (int i = 0; i < 16; ++i) {
      int r = i * 4 + w;
      f32x4 v = *(const f32x4*)(m_data + ((size_t)(b * N_ + n0 + r)) * D_ + d4 * 4);
      uint2 pp;
      pp.x = f2bf(v[0]) | ((unsigned)f2bf(v[1]) << 16);
      pp.y = f2bf(v[2]) | ((unsigned)f2bf(v[3]) << 16);
      *(uint2*)(sM + r * 528 + d4 * 8) = pp;
    }
  }
  __syncthreads();
  int lane = t & 63, w = t >> 6;
  int l15 = lane & 15, lhi = lane >> 4;
  const s16x8* A = (const s16x8*)qkbf + (size_t)b * 512;
  s16x8 areg[8];
  #pragma unroll
  for (int s = 0; s < 8; ++s) areg[s] = A[s * 64 + lane];
  f32x4 acc = {0.f, 0.f, 0.f, 0.f};
  int nrow = w * 16 + l15;
  #pragma unroll
  for (int s = 0; s < 8; ++s) {
    s16x8 bfr = *(const s16x8*)(sM + nrow * 528 + s * 64 + lhi * 16);
    acc = __builtin_amdgcn_mfma_f32_16x16x32_bf16(areg[s], bfr, acc, 0, 0, 0);
  }
  float bias = LARGE_ * (q_mask[b * N_ + n0 + nrow] - 1.f);
  float lg[4];
  #pragma unroll
  for (int r = 0; r < 4; ++r) lg[r] = (lhi < 2) ? (acc[r] + bias) : -3.4e38f;
  #pragma unroll
  for (int off = 8; off; off >>= 1)
    #pragma unroll
    for (int r = 0; r < 4; ++r) lg[r] = fmaxf(lg[r], __shfl_xor(lg[r], off));
  if (l15 == 0 && lhi < 2)
    #pragma unroll
    for (int r = 0; r < 4; ++r) red[w][lhi * 4 + r] = lg[r];
  __syncthreads();
  if (t < 8) {
    float m = fmaxf(fmaxf(red[0][t], red[1][t]), fmaxf(red[2][t], red[3][t]));
    hval[t] = m;
    mx_part[((size_t)(b * 32 + ch)) * 8 + t] = m;
  }
  __syncthreads();
  float pv[4], ps[4];
  #pragma unroll
  for (int r = 0; r < 4; ++r) {
    float M = hval[(lhi & 1) * 4 + r];
    float e = __expf(acc[r] + bias - M);
    pv[r] = e;
    ps[r] = (lhi < 2) ? e : 0.f;
  }
  if (lhi < 2) {
    f32x4 pq = {pv[0], pv[1], pv[2], pv[3]};
    pW[nrow][lhi] = pq;
  }
  #pragma unroll
  for (int off = 8; off; off >>= 1)
    #pragma unroll
    for (int r = 0; r < 4; ++r) ps[r] += __shfl_xor(ps[r], off);
  if (l15 == 0 && lhi < 2)
    #pragma unroll
    for (int r = 0; r < 4; ++r) red[w][lhi * 4 + r] = ps[r];
  __syncthreads();
  if (t < 8)
    sm_part[((size_t)(b * 32 + ch)) * 8 + t] = red[0][t] + red[1][t] + red[2][t] + red[3][t];
  f32x4 vacc[8];
  #pragma unroll
  for (int h = 0; h < 8; ++h) vacc[h] = (f32x4){0.f, 0.f, 0.f, 0.f};
  #pragma unroll 4
  for (int i = 0; i < 16; ++i) {
    int r = w * 16 + i;
    uint2 pp = *(const uint2*)(sM + r * 528 + lane * 8);
    f32x4 mv;
    mv[0] = bf2f(pp.x & 0xffff); mv[1] = bf2f(pp.x >> 16);
    mv[2] = bf2f(pp.y & 0xffff); mv[3] = bf2f(pp.y >> 16);
    f32x4 w0 = pW[r][0], w1 = pW[r][1];
    vacc[0] += mv * w0[0]; vacc[1] += mv * w0[1]; vacc[2] += mv * w0[2]; vacc[3] += mv * w0[3];
    vacc[4] += mv * w1[0]; vacc[5] += mv * w1[1]; vacc[6] += mv * w1[2]; vacc[7] += mv * w1[3];
  }
  __syncthreads();
  float* red2 = (float*)sM;
  #pragma unroll
  for (int h = 0; h < 8; ++h) *(f32x4*)(&red2[(w * 8 + h) * 256 + lane * 4]) = vacc[h];
  __syncthreads();
  float s8[8];
  #pragma unroll
  for (int h = 0; h < 8; ++h)
    s8[h] = red2[h * 256 + t] + red2[(8 + h) * 256 + t] + red2[(16 + h) * 256 + t] +
            red2[(24 + h) * 256 + t];
  uint4 u;
  u.x = f2bf(s8[0]) | ((unsigned)f2bf(s8[1]) << 16);
  u.y = f2bf(s8[2]) | ((unsigned)f2bf(s8[3]) << 16);
  u.z = f2bf(s8[4]) | ((unsigned)f2bf(s8[5]) << 16);
  u.w = f2bf(s8[6]) | ((unsigned)f2bf(s8[7]) << 16);
  *(uint4*)(wm_part + ((size_t)((b * 32 + ch) * 256 + t)) * 8) = u;
}

// ---------------- kFX: MERGED kF1+kF2 — combine chunk partials -> wa -> pack wpp
// (one launch instead of two; wa stays in LDS, no global round-trip)
__global__ void kFX(const unsigned short* __restrict__ wm_part, const float* __restrict__ mx_part,
                    const float* __restrict__ sm_part, const float* __restrict__ value_w,
                    const float* __restrict__ output_w, unsigned short* __restrict__ wpp) {
  int b = blockIdx.x, t = threadIdx.x;
  __shared__ float s_mx[256], s_sm[256], scl[256];
  __shared__ float gmx[8], gden[8];
  __shared__ float wml[8][256];
  __shared__ float sOW[32 * 260];  // padded stride: conflict-free LDS gather
  __shared__ float wa[256];
  s_mx[t] = mx_part[(size_t)b * 256 + t];
  s_sm[t] = sm_part[(size_t)b * 256 + t];
  __syncthreads();
  if (t < 8) {
    float m = -3.4e38f;
    for (int c = 0; c < 32; ++c) m = fmaxf(m, s_mx[c * 8 + t]);
    gmx[t] = m;
  }
  __syncthreads();
  scl[t] = __expf(s_mx[t] - gmx[t & 7]);
  __syncthreads();
  if (t < 8) {
    float d = 0.f;
    for (int c = 0; c < 32; ++c) d += s_sm[c * 8 + t] * scl[c * 8 + t];
    gden[t] = d;
  }
  float acc[8] = {0.f, 0.f, 0.f, 0.f, 0.f, 0.f, 0.f, 0.f};
  for (int c = 0; c < 32; ++c) {
    uint4 u = *(const uint4*)(wm_part + ((size_t)((b * 32 + c) * 256 + t)) * 8);
    const float* sc = &scl[c * 8];
    acc[0] += bf2f(u.x & 0xffff) * sc[0]; acc[1] += bf2f(u.x >> 16) * sc[1];
    acc[2] += bf2f(u.y & 0xffff) * sc[2]; acc[3] += bf2f(u.y >> 16) * sc[3];
    acc[4] += bf2f(u.z & 0xffff) * sc[4]; acc[5] += bf2f(u.z >> 16) * sc[5];
    acc[6] += bf2f(u.w & 0xffff) * sc[6]; acc[7] += bf2f(u.w >> 16) * sc[7];
  }
  #pragma unroll
  for (int h = 0; h < 8; ++h) wml[h][t] = acc[h];
  __syncthreads();
  {
    int h = t >> 5, v = t & 31;
    float s = 0.f;
    #pragma unroll 4
    for (int d = 0; d < 256; ++d) s += wml[h][d] * value_w[d * 32 + v];
    wa[t] = s / gden[h];
  }
  // pack W'[b] = diag(wa)*output_w, 8 stages of 32 output_w rows via coalesced LDS
  unsigned short* wp = wpp + (size_t)b * 65536;
  for (int sb = 0; sb < 8; ++sb) {
    __syncthreads();  // protects sOW reuse; first pass also covers wa/wm_part reads
    const f32x4* src = (const f32x4*)(output_w + sb * 32 * 256);
    #pragma unroll
    for (int i = 0; i < 8; ++i) {
      int idx4 = i * 256 + t;  // 2048 x f32x4 = 32 rows * 256 f32
      f32x4 v = src[idx4];
      int rr = idx4 >> 6, c4 = idx4 & 63;
      *(f32x4*)(&sOW[rr * 260 + c4 * 4]) = v;
    }
    __syncthreads();
    int abase = sb * 8192;
    for (int it = 0; it < 32; ++it) {
      int a = abase + it * 256 + t;
      int l = (a >> 3) & 63, j = a & 7;
      int c = (a >> 9) & 15, lh = l >> 4, ll = l & 15;
      int hvl = lh * 8 + j, o = c * 16 + ll;  // s=(a>>9)>>4 ≡ sb; hv = sb*32 + hvl
      wp[a] = f2bf(wa[sb * 32 + hvl] * sOW[hvl * 260 + o]);
    }
  }
}

// ---------------- kG: out = sigmoid(q@Wg+gb) @ W'[b] + ob  (REVERTED to 64-row R1 version)
__global__ void __launch_bounds__(256, 4) kG(
    const float* __restrict__ q_data, const float* __restrict__ gating_b,
    const float* __restrict__ output_b, const unsigned short* __restrict__ wgp,
    const unsigned short* __restrict__ wpp, float* __restrict__ out) {
  int b = blockIdx.y, row0 = blockIdx.x * 64, t = threadIdx.x;
  __shared__ __align__(16) unsigned char sG[64 * 528];
  {
    int w = t >> 6, d4 = t & 63;
    #pragma unroll
    for (int i = 0; i < 16; ++i) {
      int r = i * 4 + w;
      f32x4 v = *(const f32x4*)(q_data + ((size_t)(b * N_ + row0 + r)) * D_ + d4 * 4);
      uint2 pp;
      pp.x = f2bf(v[0]) | ((unsigned)f2bf(v[1]) << 16);
      pp.y = f2bf(v[2]) | ((unsigned)f2bf(v[3]) << 16);
      *(uint2*)(sG + r * 528 + d4 * 8) = pp;
    }
  }
  __syncthreads();
  int lane = t & 63, cg = t >> 6;
  int l15 = lane & 15, lhi = lane >> 4;
  const f32x4 z = {0.f, 0.f, 0.f, 0.f};
  f32x4 acc[16];
  #pragma unroll
  for (int f = 0; f < 16; ++f) acc[f] = z;
  const s16x8* Bg = (const s16x8*)wgp;
  #pragma unroll
  for (int s = 0; s < 8; ++s) {
    s16x8 af[4], bfr[4];
    #pragma unroll
    for (int rt = 0; rt < 4; ++rt)
      af[rt] = *(const s16x8*)(sG + (rt * 16 + l15) * 528 + s * 64 + lhi * 16);
    #pragma unroll
    for (int ct = 0; ct < 4; ++ct) bfr[ct] = Bg[(s * 16 + cg * 4 + ct) * 64 + lane];
    #pragma unroll
    for (int rt = 0; rt < 4; ++rt)
      #pragma unroll
      for (int ct = 0; ct < 4; ++ct)
        acc[rt * 4 + ct] =
            __builtin_amdgcn_mfma_f32_16x16x32_bf16(af[rt], bfr[ct], acc[rt * 4 + ct], 0, 0, 0);
  }
  __syncthreads();
  {
    float gb[4];
    #pragma unroll
    for (int ct = 0; ct < 4; ++ct) gb[ct] = gating_b[cg * 64 + ct * 16 + l15];
    #pragma unroll
    for (int rt = 0; rt < 4; ++rt)
      #pragma unroll
      for (int ct = 0; ct < 4; ++ct) {
        int col = cg * 64 + ct * 16 + l15;
        #pragma unroll
        for (int r = 0; r < 4; ++r) {
          float x = acc[rt * 4 + ct][r] + gb[ct];
          float g = 1.f / (1.f + __expf(-x));
          int row = rt * 16 + lhi * 4 + r;
          *(unsigned short*)(sG + row * 528 + col * 2) = f2bf(g);
        }
      }
  }
  __syncthreads();
  #pragma unroll
  for (int f = 0; f < 16; ++f) acc[f] = z;
  const s16x8* Bp = (const s16x8*)wpp + (size_t)b * 8192;
  #pragma unroll
  for (int s = 0; s < 8; ++s) {
    s16x8 af[4], bfr[4];
    #pragma unroll
    for (int rt = 0; rt < 4; ++rt)
      af[rt] = *(const s16x8*)(sG + (rt * 16 + l15) * 528 + s * 64 + lhi * 16);
    #pragma unroll
    for (int ct = 0; ct < 4; ++ct) bfr[ct] = Bp[(s * 16 + cg * 4 + ct) * 64 + lane];
    #pragma unroll
    for (int rt = 0; rt < 4; ++rt)
      #pragma unroll
      for (int ct = 0; ct < 4; ++ct)
        acc[rt * 4 + ct] =
            __builtin_amdgcn_mfma_f32_16x16x32_bf16(af[rt], bfr[ct], acc[rt * 4 + ct], 0, 0, 0);
  }
  __syncthreads();
  float* fOut = (float*)sG;
  float ob[4];
  #pragma unroll
  for (int ct = 0; ct < 4; ++ct) ob[ct] = output_b[cg * 64 + ct * 16 + l15];
  #pragma unroll
  for (int p = 0; p < 2; ++p) {
    #pragma unroll
    for (int rt2 = 0; rt2 < 2; ++rt2) {
      int rt = p * 2 + rt2;
      #pragma unroll
      for (int ct = 0; ct < 4; ++ct) {
        int col = cg * 64 + ct * 16 + l15;
        #pragma unroll
        for (int r = 0; r < 4; ++r)
          fOut[(rt2 * 16 + lhi * 4 + r) * 260 + col] = acc[rt * 4 + ct][r] + ob[ct];
      }
    }
    __syncthreads();
    {
      int w = t >> 6, c4 = t & 63;
      #pragma unroll
      for (int j = 0; j < 8; ++j) {
        int r32 = j * 4 + w;
        f32x4 v = *(const f32x4*)(fOut + r32 * 260 + c4 * 4);
        *(f32x4*)(out + ((size_t)(b * N_ + row0 + p * 32 + r32)) * D_ + c4 * 4) = v;
      }
    }
    __syncthreads();
  }
}

extern "C" void kernel_launch(void* const* d_in, const int* in_sizes, int n_in,
                              void* d_out, int out_size, void* d_ws, size_t ws_size,
                              hipStream_t stream) {
  const float* q_data   = (const float*)d_in[0];
  const float* m_data   = (const float*)d_in[1];
  const float* q_mask   = (const float*)d_in[2];
  const float* query_w  = (const float*)d_in[3];
  const float* key_w    = (const float*)d_in[4];
  const float* value_w  = (const float*)d_in[5];
  const float* gating_w = (const float*)d_in[6];
  const float* gating_b = (const float*)d_in[7];
  const float* output_w = (const float*)d_in[8];
  const float* output_b = (const float*)d_in[9];
  float* out = (float*)d_out;
  char* ws = (char*)d_ws;

  unsigned short* qkbf = (unsigned short*)(ws + WS_QKBF);
  unsigned short* wgp  = (unsigned short*)(ws + WS_WGP);
  float* qpart = (float*)(ws + WS_QPART);
  float* mpart = (float*)(ws + WS_MPART);
  float* mx    = (float*)(ws + WS_MX);
  float* sm    = (float*)(ws + WS_SM);
  unsigned short* wmp = (unsigned short*)(ws + WS_WMP);
  unsigned short* wpp = (unsigned short*)(ws + WS_WPP);

  kA<<<576, 256, 0, stream>>>(q_data, q_mask, gating_w, qpart, mpart, wgp);
  kB<<<64, 256, 0, stream>>>(qpart, mpart, query_w, key_w, qkbf);
  kM<<<dim3(32, 64), 256, 0, stream>>>(m_data, q_mask, qkbf, wmp, mx, sm);
  kFX<<<64, 256, 0, stream>>>(wmp, mx, sm, value_w, output_w, wpp);
  kG<<<dim3(32, 64), 256, 0, stream>>>(q_data, gating_b, output_b, wgp, wpp, out);
}

// Round 4
// 474.508 us; speedup vs baseline: 1.0598x; 1.0248x over previous
//
#include <hip/hip_runtime.h>

#define B_ 64
#define N_ 2048
#define D_ 256
#define H_ 8
#define LARGE_ 1e9f
#define EPS_ 1e-10f

typedef __attribute__((ext_vector_type(4))) float f32x4;
typedef __attribute__((ext_vector_type(8))) short s16x8;

// workspace layout (bytes) — total 11,345,920 (< 15.4 MB proven available)
#define WS_QKBF 0          // qk A-frag bf16: 64 b * 8 kblk * 64 lane * 8 = 524288
#define WS_WGP  524288     // gating_w pack bf16 = 131072 (ends 655360)
#define WS_QPART 655360    // q partial sums [2048][256] f32 = 2097152 (ends 2752512)
#define WS_MPART 2752512   // mask partial sums [2048] f32 = 8192 (ends 2760704)
#define WS_MX   2760704    // chunk max [64][32][8] f32 = 65536 (ends 2826240)
#define WS_SM   2826240    // chunk expsum [64][32][8] f32 = 65536 (ends 2891776)
#define WS_WA   2891776    // combined weighted_avg [64][256] f32 = 65536 (ends 2957312)
#define WS_WMP  2957312    // wm partials bf16 [64*32][256][8] = 8388608 (ends 11345920)
#define WS_WPP  2957312    // per-batch output pack bf16 = 8388608 — overlays WS_WMP
                           // (wm_part dead after kF1 completes; kF2 writes wpp — safe
                           //  across the kF1/kF2 kernel boundary)

__device__ __forceinline__ unsigned short f2bf(float f) {
  union { float f; unsigned u; } v; v.f = f;
  unsigned r = v.u + 0x7fffu + ((v.u >> 16) & 1u);
  return (unsigned short)(r >> 16);
}
__device__ __forceinline__ float bf2f(unsigned short s) {
  union { unsigned u; float f; } v; v.u = ((unsigned)s) << 16;
  return v.f;
}

// ---------------- kA: masked q-sum partials — 2048 blocks (4x occupancy vs 512) + Wg pack
__global__ void kA(const float* __restrict__ q_data, const float* __restrict__ q_mask,
                   const float* __restrict__ gating_w, float* __restrict__ qpart,
                   float* __restrict__ mpart, unsigned short* __restrict__ wgp) {
  int blk = blockIdx.x, t = threadIdx.x;
  if (blk < 2048) {
    int b = blk >> 5, n0 = (blk & 31) * 64;
    __shared__ float msk[64];
    __shared__ float qred[4][256];
    if (t < 64) msk[t] = q_mask[b * N_ + n0 + t];
    __syncthreads();
    int w = t >> 6, d4 = t & 63;
    const float* qbase = q_data + ((size_t)(b * N_ + n0)) * D_;
    f32x4 acc = {0.f, 0.f, 0.f, 0.f};
    #pragma unroll 4
    for (int i = 0; i < 16; ++i) {
      int r = i * 4 + w;
      f32x4 v = *(const f32x4*)(qbase + (size_t)r * D_ + d4 * 4);
      acc += v * msk[r];
    }
    *(f32x4*)(&qred[w][d4 * 4]) = acc;
    __syncthreads();
    qpart[((size_t)blk) * 256 + t] = qred[0][t] + qred[1][t] + qred[2][t] + qred[3][t];
    if (t < 64) {
      float mv = msk[t];
      for (int off = 32; off; off >>= 1) mv += __shfl_xor(mv, off);
      if (t == 0) mpart[blk] = mv;
    }
  } else {
    int base = (blk - 2048) * 1024;
    for (int i = 0; i < 4; ++i) {
      int a = base + i * 256 + t;
      int sc = a >> 9, l = (a >> 3) & 63, j = a & 7;
      int s = sc >> 4, c = sc & 15, lh = l >> 4, ll = l & 15;
      int k = s * 32 + lh * 8 + j, n = c * 16 + ll;
      wgp[a] = f2bf(gating_w[k * 256 + n]);
    }
  }
}

// ---------------- kB: reduce 32 partials -> q_avg -> q -> qk bf16 A-frag
__global__ void kB(const float* __restrict__ qpart, const float* __restrict__ mpart,
                   const float* __restrict__ query_w, const float* __restrict__ key_w,
                   unsigned short* __restrict__ qkbf) {
  int b = blockIdx.x, t = threadIdx.x;
  __shared__ float qa[256];
  __shared__ float ql[256];
  float s = 0.f;
  #pragma unroll
  for (int p = 0; p < 32; ++p) s += qpart[((size_t)(b * 32 + p)) * 256 + t];
  float ms = 0.f;
  #pragma unroll
  for (int p = 0; p < 32; ++p) ms += mpart[b * 32 + p];
  qa[t] = s / (ms + EPS_);
  __syncthreads();
  float acc = 0.f;
  #pragma unroll 4
  for (int a = 0; a < 256; ++a) acc += qa[a] * query_w[a * 256 + t];
  ql[t] = acc * 0.17677669529663687f;  // * KD^-0.5
  __syncthreads();
  float v8[8];
  #pragma unroll
  for (int h = 0; h < 8; ++h) {
    float v = 0.f;
    #pragma unroll
    for (int c = 0; c < 32; ++c) v += key_w[t * 32 + c] * ql[h * 32 + c];
    v8[h] = v;
  }
  int si = t >> 5, lh = (t >> 3) & 3, j = t & 7;
  unsigned short* base = qkbf + ((size_t)(b * 8 + si) * 64) * 8;
  #pragma unroll
  for (int h = 0; h < 8; ++h) {
    base[(lh * 16 + h) * 8 + j] = f2bf(v8[h]);
    base[(lh * 16 + 8 + h) * 8 + j] = 0;
  }
}

// ---------------- kM: FUSED logits(MFMA) + online softmax + weighted partial sum (UNCHANGED)
__global__ void kM(const float* __restrict__ m_data, const float* __restrict__ q_mask,
                   const unsigned short* __restrict__ qkbf, unsigned short* __restrict__ wm_part,
                   float* __restrict__ mx_part, float* __restrict__ sm_part) {
  int b = blockIdx.y, ch = blockIdx.x, n0 = ch * 64, t = threadIdx.x;
  __shared__ __align__(16) unsigned char sM[64 * 528];
  __shared__ f32x4 pW[64][2];   // exp weights per row: [0]=h0..3, [1]=h4..7
  __shared__ float red[4][8];
  __shared__ float hval[8];
  {
    int w = t >> 6, d4 = t & 63;
    #pragma unroll
    for (int i = 0; i < 16; ++i) {
      int r = i * 4 + w;
      f32x4 v = *(const f32x4*)(m_data + ((size_t)(b * N_ + n0 + r)) * D_ + d4 * 4);
      uint2 pp;
      pp.x = f2bf(v[0]) | ((unsigned)f2bf(v[1]) << 16);
      pp.y = f2bf(v[2]) | ((unsigned)f2bf(v[3]) << 16);
      *(uint2*)(sM + r * 528 + d4 * 8) = pp;
    }
  }
  __syncthreads();
  int lane = t & 63, w = t >> 6;
  int l15 = lane & 15, lhi = lane >> 4;
  const s16x8* A = (const s16x8*)qkbf + (size_t)b * 512;
  s16x8 areg[8];
  #pragma unroll
  for (int s = 0; s < 8; ++s) areg[s] = A[s * 64 + lane];
  f32x4 acc = {0.f, 0.f, 0.f, 0.f};
  int nrow = w * 16 + l15;
  #pragma unroll
  for (int s = 0; s < 8; ++s) {
    s16x8 bfr = *(const s16x8*)(sM + nrow * 528 + s * 64 + lhi * 16);
    acc = __builtin_amdgcn_mfma_f32_16x16x32_bf16(areg[s], bfr, acc, 0, 0, 0);
  }
  float bias = LARGE_ * (q_mask[b * N_ + n0 + nrow] - 1.f);
  float lg[4];
  #pragma unroll
  for (int r = 0; r < 4; ++r) lg[r] = (lhi < 2) ? (acc[r] + bias) : -3.4e38f;
  #pragma unroll
  for (int off = 8; off; off >>= 1)
    #pragma unroll
    for (int r = 0; r < 4; ++r) lg[r] = fmaxf(lg[r], __shfl_xor(lg[r], off));
  if (l15 == 0 && lhi < 2)
    #pragma unroll
    for (int r = 0; r < 4; ++r) red[w][lhi * 4 + r] = lg[r];
  __syncthreads();
  if (t < 8) {
    float m = fmaxf(fmaxf(red[0][t], red[1][t]), fmaxf(red[2][t], red[3][t]));
    hval[t] = m;
    mx_part[((size_t)(b * 32 + ch)) * 8 + t] = m;
  }
  __syncthreads();
  float pv[4], ps[4];
  #pragma unroll
  for (int r = 0; r < 4; ++r) {
    float M = hval[(lhi & 1) * 4 + r];
    float e = __expf(acc[r] + bias - M);
    pv[r] = e;
    ps[r] = (lhi < 2) ? e : 0.f;
  }
  if (lhi < 2) {
    f32x4 pq = {pv[0], pv[1], pv[2], pv[3]};
    pW[nrow][lhi] = pq;
  }
  #pragma unroll
  for (int off = 8; off; off >>= 1)
    #pragma unroll
    for (int r = 0; r < 4; ++r) ps[r] += __shfl_xor(ps[r], off);
  if (l15 == 0 && lhi < 2)
    #pragma unroll
    for (int r = 0; r < 4; ++r) red[w][lhi * 4 + r] = ps[r];
  __syncthreads();
  if (t < 8)
    sm_part[((size_t)(b * 32 + ch)) * 8 + t] = red[0][t] + red[1][t] + red[2][t] + red[3][t];
  f32x4 vacc[8];
  #pragma unroll
  for (int h = 0; h < 8; ++h) vacc[h] = (f32x4){0.f, 0.f, 0.f, 0.f};
  #pragma unroll 4
  for (int i = 0; i < 16; ++i) {
    int r = w * 16 + i;
    uint2 pp = *(const uint2*)(sM + r * 528 + lane * 8);
    f32x4 mv;
    mv[0] = bf2f(pp.x & 0xffff); mv[1] = bf2f(pp.x >> 16);
    mv[2] = bf2f(pp.y & 0xffff); mv[3] = bf2f(pp.y >> 16);
    f32x4 w0 = pW[r][0], w1 = pW[r][1];
    vacc[0] += mv * w0[0]; vacc[1] += mv * w0[1]; vacc[2] += mv * w0[2]; vacc[3] += mv * w0[3];
    vacc[4] += mv * w1[0]; vacc[5] += mv * w1[1]; vacc[6] += mv * w1[2]; vacc[7] += mv * w1[3];
  }
  __syncthreads();
  float* red2 = (float*)sM;
  #pragma unroll
  for (int h = 0; h < 8; ++h) *(f32x4*)(&red2[(w * 8 + h) * 256 + lane * 4]) = vacc[h];
  __syncthreads();
  float s8[8];
  #pragma unroll
  for (int h = 0; h < 8; ++h)
    s8[h] = red2[h * 256 + t] + red2[(8 + h) * 256 + t] + red2[(16 + h) * 256 + t] +
            red2[(24 + h) * 256 + t];
  uint4 u;
  u.x = f2bf(s8[0]) | ((unsigned)f2bf(s8[1]) << 16);
  u.y = f2bf(s8[2]) | ((unsigned)f2bf(s8[3]) << 16);
  u.z = f2bf(s8[4]) | ((unsigned)f2bf(s8[5]) << 16);
  u.w = f2bf(s8[6]) | ((unsigned)f2bf(s8[7]) << 16);
  *(uint4*)(wm_part + ((size_t)((b * 32 + ch) * 256 + t)) * 8) = u;
}

// ---------------- kF1: combine chunk partials with max-rescale -> wa (R2 version)
__global__ void kF1(const unsigned short* __restrict__ wm_part, const float* __restrict__ mx_part,
                    const float* __restrict__ sm_part, const float* __restrict__ value_w,
                    float* __restrict__ wa_g) {
  int b = blockIdx.x, t = threadIdx.x;
  __shared__ float s_mx[256], s_sm[256], scl[256];
  __shared__ float gmx[8], gden[8];
  __shared__ float wml[8][256];
  s_mx[t] = mx_part[(size_t)b * 256 + t];
  s_sm[t] = sm_part[(size_t)b * 256 + t];
  __syncthreads();
  if (t < 8) {
    float m = -3.4e38f;
    for (int c = 0; c < 32; ++c) m = fmaxf(m, s_mx[c * 8 + t]);
    gmx[t] = m;
  }
  __syncthreads();
  scl[t] = __expf(s_mx[t] - gmx[t & 7]);
  __syncthreads();
  if (t < 8) {
    float d = 0.f;
    for (int c = 0; c < 32; ++c) d += s_sm[c * 8 + t] * scl[c * 8 + t];
    gden[t] = d;
  }
  float acc[8] = {0.f, 0.f, 0.f, 0.f, 0.f, 0.f, 0.f, 0.f};
  for (int c = 0; c < 32; ++c) {
    uint4 u = *(const uint4*)(wm_part + ((size_t)((b * 32 + c) * 256 + t)) * 8);
    const float* sc = &scl[c * 8];
    acc[0] += bf2f(u.x & 0xffff) * sc[0]; acc[1] += bf2f(u.x >> 16) * sc[1];
    acc[2] += bf2f(u.y & 0xffff) * sc[2]; acc[3] += bf2f(u.y >> 16) * sc[3];
    acc[4] += bf2f(u.z & 0xffff) * sc[4]; acc[5] += bf2f(u.z >> 16) * sc[5];
    acc[6] += bf2f(u.w & 0xffff) * sc[6]; acc[7] += bf2f(u.w >> 16) * sc[7];
  }
  #pragma unroll
  for (int h = 0; h < 8; ++h) wml[h][t] = acc[h];
  __syncthreads();
  int h = t >> 5, v = t & 31;
  float s = 0.f;
  #pragma unroll 4
  for (int d = 0; d < 256; ++d) s += wml[h][d] * value_w[d * 32 + v];
  wa_g[b * 256 + t] = s / gden[h];
}

// ---------------- kF2: pack W'[b] = diag(wa)*output_w, staged coalesced LDS (R2 version)
__global__ void kF2(const float* __restrict__ wa_g, const float* __restrict__ output_w,
                    unsigned short* __restrict__ wpp) {
  int blk = blockIdx.x, t = threadIdx.x;
  int b = blk >> 2, quad = blk & 3;
  __shared__ float sOW[32 * 260];  // stride 260 f32: 16B-aligned rows, conflict-free gather
  __shared__ float wa[256];
  wa[t] = wa_g[b * 256 + t];
  unsigned short* wp = wpp + (size_t)b * 65536;
  for (int half = 0; half < 2; ++half) {
    int srow = quad * 64 + half * 32;  // = s*32 for s = 2*quad + half
    __syncthreads();                    // protects sOW reuse; covers wa on first pass
    const f32x4* src = (const f32x4*)(output_w + srow * 256);
    #pragma unroll
    for (int i = 0; i < 8; ++i) {
      int idx4 = i * 256 + t;           // 2048 x f32x4 = 32 rows * 256 f32
      f32x4 v = src[idx4];
      int rr = idx4 >> 6, c4 = idx4 & 63;
      *(f32x4*)(&sOW[rr * 260 + c4 * 4]) = v;
    }
    __syncthreads();
    int abase = quad * 16384 + half * 8192;
    for (int it = 0; it < 32; ++it) {
      int a = abase + it * 256 + t;
      int l = (a >> 3) & 63, j = a & 7;
      int c = (a >> 9) & 15, lh = l >> 4, ll = l & 15;
      int hvl = lh * 8 + j, o = c * 16 + ll;  // hv = srow + hvl
      wp[a] = f2bf(wa[srow + hvl] * sOW[hvl * 260 + o]);
    }
  }
}

// ---------------- kG: out = sigmoid(q@Wg+gb) @ W'[b] + ob  (UNCHANGED — 64-row, control)
__global__ void __launch_bounds__(256, 4) kG(
    const float* __restrict__ q_data, const float* __restrict__ gating_b,
    const float* __restrict__ output_b, const unsigned short* __restrict__ wgp,
    const unsigned short* __restrict__ wpp, float* __restrict__ out) {
  int b = blockIdx.y, row0 = blockIdx.x * 64, t = threadIdx.x;
  __shared__ __align__(16) unsigned char sG[64 * 528];
  {
    int w = t >> 6, d4 = t & 63;
    #pragma unroll
    for (int i = 0; i < 16; ++i) {
      int r = i * 4 + w;
      f32x4 v = *(const f32x4*)(q_data + ((size_t)(b * N_ + row0 + r)) * D_ + d4 * 4);
      uint2 pp;
      pp.x = f2bf(v[0]) | ((unsigned)f2bf(v[1]) << 16);
      pp.y = f2bf(v[2]) | ((unsigned)f2bf(v[3]) << 16);
      *(uint2*)(sG + r * 528 + d4 * 8) = pp;
    }
  }
  __syncthreads();
  int lane = t & 63, cg = t >> 6;
  int l15 = lane & 15, lhi = lane >> 4;
  const f32x4 z = {0.f, 0.f, 0.f, 0.f};
  f32x4 acc[16];
  #pragma unroll
  for (int f = 0; f < 16; ++f) acc[f] = z;
  const s16x8* Bg = (const s16x8*)wgp;
  #pragma unroll
  for (int s = 0; s < 8; ++s) {
    s16x8 af[4], bfr[4];
    #pragma unroll
    for (int rt = 0; rt < 4; ++rt)
      af[rt] = *(const s16x8*)(sG + (rt * 16 + l15) * 528 + s * 64 + lhi * 16);
    #pragma unroll
    for (int ct = 0; ct < 4; ++ct) bfr[ct] = Bg[(s * 16 + cg * 4 + ct) * 64 + lane];
    #pragma unroll
    for (int rt = 0; rt < 4; ++rt)
      #pragma unroll
      for (int ct = 0; ct < 4; ++ct)
        acc[rt * 4 + ct] =
            __builtin_amdgcn_mfma_f32_16x16x32_bf16(af[rt], bfr[ct], acc[rt * 4 + ct], 0, 0, 0);
  }
  __syncthreads();
  {
    float gb[4];
    #pragma unroll
    for (int ct = 0; ct < 4; ++ct) gb[ct] = gating_b[cg * 64 + ct * 16 + l15];
    #pragma unroll
    for (int rt = 0; rt < 4; ++rt)
      #pragma unroll
      for (int ct = 0; ct < 4; ++ct) {
        int col = cg * 64 + ct * 16 + l15;
        #pragma unroll
        for (int r = 0; r < 4; ++r) {
          float x = acc[rt * 4 + ct][r] + gb[ct];
          float g = 1.f / (1.f + __expf(-x));
          int row = rt * 16 + lhi * 4 + r;
          *(unsigned short*)(sG + row * 528 + col * 2) = f2bf(g);
        }
      }
  }
  __syncthreads();
  #pragma unroll
  for (int f = 0; f < 16; ++f) acc[f] = z;
  const s16x8* Bp = (const s16x8*)wpp + (size_t)b * 8192;
  #pragma unroll
  for (int s = 0; s < 8; ++s) {
    s16x8 af[4], bfr[4];
    #pragma unroll
    for (int rt = 0; rt < 4; ++rt)
      af[rt] = *(const s16x8*)(sG + (rt * 16 + l15) * 528 + s * 64 + lhi * 16);
    #pragma unroll
    for (int ct = 0; ct < 4; ++ct) bfr[ct] = Bp[(s * 16 + cg * 4 + ct) * 64 + lane];
    #pragma unroll
    for (int rt = 0; rt < 4; ++rt)
      #pragma unroll
      for (int ct = 0; ct < 4; ++ct)
        acc[rt * 4 + ct] =
            __builtin_amdgcn_mfma_f32_16x16x32_bf16(af[rt], bfr[ct], acc[rt * 4 + ct], 0, 0, 0);
  }
  __syncthreads();
  float* fOut = (float*)sG;
  float ob[4];
  #pragma unroll
  for (int ct = 0; ct < 4; ++ct) ob[ct] = output_b[cg * 64 + ct * 16 + l15];
  #pragma unroll
  for (int p = 0; p < 2; ++p) {
    #pragma unroll
    for (int rt2 = 0; rt2 < 2; ++rt2) {
      int rt = p * 2 + rt2;
      #pragma unroll
      for (int ct = 0; ct < 4; ++ct) {
        int col = cg * 64 + ct * 16 + l15;
        #pragma unroll
        for (int r = 0; r < 4; ++r)
          fOut[(rt2 * 16 + lhi * 4 + r) * 260 + col] = acc[rt * 4 + ct][r] + ob[ct];
      }
    }
    __syncthreads();
    {
      int w = t >> 6, c4 = t & 63;
      #pragma unroll
      for (int j = 0; j < 8; ++j) {
        int r32 = j * 4 + w;
        f32x4 v = *(const f32x4*)(fOut + r32 * 260 + c4 * 4);
        *(f32x4*)(out + ((size_t)(b * N_ + row0 + p * 32 + r32)) * D_ + c4 * 4) = v;
      }
    }
    __syncthreads();
  }
}

extern "C" void kernel_launch(void* const* d_in, const int* in_sizes, int n_in,
                              void* d_out, int out_size, void* d_ws, size_t ws_size,
                              hipStream_t stream) {
  const float* q_data   = (const float*)d_in[0];
  const float* m_data   = (const float*)d_in[1];
  const float* q_mask   = (const float*)d_in[2];
  const float* query_w  = (const float*)d_in[3];
  const float* key_w    = (const float*)d_in[4];
  const float* value_w  = (const float*)d_in[5];
  const float* gating_w = (const float*)d_in[6];
  const float* gating_b = (const float*)d_in[7];
  const float* output_w = (const float*)d_in[8];
  const float* output_b = (const float*)d_in[9];
  float* out = (float*)d_out;
  char* ws = (char*)d_ws;

  unsigned short* qkbf = (unsigned short*)(ws + WS_QKBF);
  unsigned short* wgp  = (unsigned short*)(ws + WS_WGP);
  float* qpart = (float*)(ws + WS_QPART);
  float* mpart = (float*)(ws + WS_MPART);
  float* mx    = (float*)(ws + WS_MX);
  float* sm    = (float*)(ws + WS_SM);
  float* wa    = (float*)(ws + WS_WA);
  unsigned short* wmp = (unsigned short*)(ws + WS_WMP);
  unsigned short* wpp = (unsigned short*)(ws + WS_WPP);

  kA<<<2112, 256, 0, stream>>>(q_data, q_mask, gating_w, qpart, mpart, wgp);
  kB<<<64, 256, 0, stream>>>(qpart, mpart, query_w, key_w, qkbf);
  kM<<<dim3(32, 64), 256, 0, stream>>>(m_data, q_mask, qkbf, wmp, mx, sm);
  kF1<<<64, 256, 0, stream>>>(wmp, mx, sm, value_w, wa);
  kF2<<<256, 256, 0, stream>>>(wa, output_w, wpp);
  kG<<<dim3(32, 64), 256, 0, stream>>>(q_data, gating_b, output_b, wgp, wpp, out);
}